// Round 4
// baseline (92.334 us; speedup 1.0000x reference)
//
#include <hip/hip_runtime.h>
#include <hip/hip_bf16.h>
#include <stdint.h>

// out[b,o,k] = sum_{h,m} W[o, h*64+m] * xl[b,h,k] * x0[b,m,k] + bias[o]
// B=256, M=H=64, K=128, OUT=256, C=4096.
// v4: out = sum_h xl[h,n] * (W_h @ x0) with 32x32x16 MFMA.
//  - 256 blocks (one per b), 8 waves; wave w owns o-rows [32w,32w+32), all 128 k.
//  - x0 B-frags (bf16) h-invariant in registers (64 VGPR).
//  - W pre-tiled bf16 in d_ws; 4-deep LDS buffers, global_load_lds(16B),
//    raw s_barrier + counted vmcnt(8) (never drained in-loop), stage h+3/iter.
//  - xl bf16 in LDS; per-h per-wave: 4 ds_read_b128 + 4 ds_read_u16 +
//    16 MFMA(32x32x16) + 64 v_fma.

typedef __attribute__((ext_vector_type(8)))  short short8;
typedef __attribute__((ext_vector_type(16))) float f32x16;

#define B_SZ   256
#define K_SZ   128
#define OUT_SZ 256
#define C_SZ   4096
#define NH     64

__device__ __forceinline__ uint32_t pack_bf16(float a, float b) {
    __hip_bfloat162 h2 = __float22bfloat162_rn(make_float2(a, b));
    union { __hip_bfloat162 h; uint32_t u; } v;
    v.h = h2;
    return v.u;
}

__device__ __forceinline__ float bf2f(short s) {
    union { uint32_t u; float f; } v;
    v.u = ((uint32_t)(uint16_t)s) << 16;
    return v.f;
}

__device__ __forceinline__ void load_lds_16(const void* g, void* l) {
    __builtin_amdgcn_global_load_lds(
        (const __attribute__((address_space(1))) unsigned int*)g,
        (__attribute__((address_space(3))) unsigned int*)l,
        16, 0, 0);
}

// ---- W f32 -> bf16 tiled for 32x32x16 A-frags ----
// subtile = (g_ot8 * 256 + cb16), 512 shorts, lane-linear:
//   element (o = g_ot8*32 + (lane&31), c = cb16*16 + (lane>>5)*8 + j)
__global__ void convert_W_tiled(const float* __restrict__ W, short* __restrict__ Wb) {
    int t = blockIdx.x * blockDim.x + threadIdx.x;   // 0..131071
    int lane = t & 63;
    int sub  = t >> 6;          // 0..2047
    int cb16 = sub & 255;
    int got  = sub >> 8;        // 0..7
    int o = got * 32 + (lane & 31);
    int c = cb16 * 16 + (lane >> 5) * 8;
    const float* p = W + (size_t)o * C_SZ + c;
    float4 w0 = *(const float4*)p;
    float4 w1 = *(const float4*)(p + 4);
    union { short8 s; uint32_t u[4]; } cc;
    cc.u[0] = pack_bf16(w0.x, w0.y);
    cc.u[1] = pack_bf16(w0.z, w0.w);
    cc.u[2] = pack_bf16(w1.x, w1.y);
    cc.u[3] = pack_bf16(w1.z, w1.w);
    *(short8*)(Wb + (size_t)t * 8) = cc.s;
}

template<bool USE_WS>
__global__ __launch_bounds__(512, 2)
void cin_main(const float* __restrict__ x0, const float* __restrict__ xl,
              const float* __restrict__ Wf, const short* __restrict__ Wb,
              const float* __restrict__ bias, float* __restrict__ out) {
    __shared__ short Wlds[4 * 16384];   // 4 bufs x 32KB (16384 shorts each)
    __shared__ short xls[NH * K_SZ];    // 16KB bf16 [h][k]

    const int b    = blockIdx.x;
    const int tid  = threadIdx.x;
    const int lane = tid & 63;
    const int wave = tid >> 6;          // o-tile 0..7
    const int l31  = lane & 31;
    const int hi   = lane >> 5;         // 0..1

    // ---- stage xl as bf16 into LDS (512 thr x 16 elems) ----
    {
        const float4* src = (const float4*)(xl + (size_t)b * (NH * K_SZ));
        float4 v[4];
#pragma unroll
        for (int i = 0; i < 4; ++i) v[i] = src[tid * 4 + i];
        uint32_t* dst = (uint32_t*)&xls[tid * 16];
#pragma unroll
        for (int i = 0; i < 4; ++i) {
            dst[2 * i]     = pack_bf16(v[i].x, v[i].y);
            dst[2 * i + 1] = pack_bf16(v[i].z, v[i].w);
        }
    }

    // ---- x0 B-frags (h-invariant), 32x32x16 layout: 64 VGPRs ----
    // x0p[s][nt].j = x0[m = s*16 + hi*8 + j][n = nt*32 + l31]
    union { short8 s; uint32_t u[4]; } x0p[4][4];
    {
        const float* x0b = x0 + (size_t)b * (64 * K_SZ);
#pragma unroll
        for (int s = 0; s < 4; ++s)
#pragma unroll
            for (int nt = 0; nt < 4; ++nt)
#pragma unroll
                for (int t2 = 0; t2 < 4; ++t2) {
                    const int m0 = s * 16 + hi * 8 + 2 * t2;
                    const int cc = nt * 32 + l31;
                    x0p[s][nt].u[t2] = pack_bf16(x0b[m0 * K_SZ + cc],
                                                 x0b[(m0 + 1) * K_SZ + cc]);
                }
    }

    // ---- W staging: wave w stages its own 4 subtiles (g_ot8=w, cb16=4h..4h+3) ----
    const short* wsrc = Wb + ((size_t)wave * 256) * 512 + lane * 8;
    const float* wfrow = Wf + (size_t)(wave * 32 + l31) * C_SZ + hi * 8;

    auto stage = [&](int buf, int h) {
        short* d = Wlds + buf * 16384 + wave * 2048;
        if (USE_WS) {
            const short* s0 = wsrc + (size_t)(4 * h) * 512;
#pragma unroll
            for (int cbl = 0; cbl < 4; ++cbl)
                load_lds_16(s0 + cbl * 512, d + cbl * 512);
        } else {
#pragma unroll
            for (int cbl = 0; cbl < 4; ++cbl) {
                const float* p = wfrow + h * 64 + cbl * 16;
                float4 w0 = *(const float4*)p;
                float4 w1 = *(const float4*)(p + 4);
                union { short8 s; uint32_t u[4]; } cc;
                cc.u[0] = pack_bf16(w0.x, w0.y);
                cc.u[1] = pack_bf16(w0.z, w0.w);
                cc.u[2] = pack_bf16(w1.x, w1.y);
                cc.u[3] = pack_bf16(w1.z, w1.w);
                *(short8*)(d + cbl * 512 + lane * 8) = cc.s;
            }
        }
    };

    f32x16 acc[4];
#pragma unroll
    for (int nt = 0; nt < 4; ++nt)
#pragma unroll
        for (int r = 0; r < 16; ++r) acc[nt][r] = 0.f;
    f32x16 kz;
#pragma unroll
    for (int r = 0; r < 16; ++r) kz[r] = 0.f;

    __syncthreads();            // xl visible to all waves; drains prologue vmem
    stage(0, 0);
    stage(1, 1);
    stage(2, 2);                // 12 loads in flight (USE_WS path)

    for (int h = 0; h < NH; ++h) {
        if (!USE_WS) asm volatile("s_waitcnt lgkmcnt(0)" ::: "memory");
        asm volatile("s_waitcnt vmcnt(8)" ::: "memory");   // h's 4 loads done
        __builtin_amdgcn_s_barrier();

        // issue stage for h+3 (wraps harmlessly at tail)
        stage((h + 3) & 3, (h + 3) & (NH - 1));

        // W A-frags for this h
        const short* wb2 = Wlds + (h & 3) * 16384 + wave * 2048 + lane * 8;
        const short8 af0 = *(const short8*)(wb2);
        const short8 af1 = *(const short8*)(wb2 + 512);
        const short8 af2 = *(const short8*)(wb2 + 1024);
        const short8 af3 = *(const short8*)(wb2 + 1536);

        // xl scalars (one per n-tile; lanes l and l+32 broadcast)
        float xlv[4];
#pragma unroll
        for (int nt = 0; nt < 4; ++nt)
            xlv[nt] = bf2f(xls[h * K_SZ + nt * 32 + l31]);

        __builtin_amdgcn_s_setprio(1);
#pragma unroll
        for (int nt = 0; nt < 4; ++nt) {
            f32x16 g = __builtin_amdgcn_mfma_f32_32x32x16_bf16(af0, x0p[0][nt].s, kz, 0, 0, 0);
            g = __builtin_amdgcn_mfma_f32_32x32x16_bf16(af1, x0p[1][nt].s, g, 0, 0, 0);
            g = __builtin_amdgcn_mfma_f32_32x32x16_bf16(af2, x0p[2][nt].s, g, 0, 0, 0);
            g = __builtin_amdgcn_mfma_f32_32x32x16_bf16(af3, x0p[3][nt].s, g, 0, 0, 0);
#pragma unroll
            for (int r = 0; r < 16; ++r)
                acc[nt][r] += xlv[nt] * g[r];
        }
        __builtin_amdgcn_s_setprio(0);
    }

    // ---- epilogue: bias + store ----
    // 32x32 C/D: col(k) = l31, row(o) = (r&3) + 8*(r>>2) + 4*hi   [m74/m101]
    float bv[16];
#pragma unroll
    for (int r = 0; r < 16; ++r)
        bv[r] = bias[wave * 32 + (r & 3) + 8 * (r >> 2) + 4 * hi];

    float* outb = out + (size_t)b * (OUT_SZ * K_SZ);
#pragma unroll
    for (int nt = 0; nt < 4; ++nt) {
        const int kcol = nt * 32 + l31;
#pragma unroll
        for (int r = 0; r < 16; ++r) {
            const int orow = wave * 32 + (r & 3) + 8 * (r >> 2) + 4 * hi;
            outb[orow * K_SZ + kcol] = acc[nt][r] + bv[r];
        }
    }
}

extern "C" void kernel_launch(void* const* d_in, const int* in_sizes, int n_in,
                              void* d_out, int out_size, void* d_ws, size_t ws_size,
                              hipStream_t stream) {
    const float* x0   = (const float*)d_in[0];
    const float* xl   = (const float*)d_in[1];
    // d_in[2] is the scalar k (=128) — fixed by the problem shape
    const float* W    = (const float*)d_in[3];
    const float* bias = (const float*)d_in[4];
    float* out = (float*)d_out;

    const size_t w_bytes = (size_t)OUT_SZ * C_SZ * sizeof(short);
    short* Wb = (short*)d_ws;

    if (ws_size >= w_bytes) {
        convert_W_tiled<<<dim3(512), dim3(256), 0, stream>>>(W, Wb);
        cin_main<true><<<dim3(B_SZ), dim3(512), 0, stream>>>(x0, xl, W, Wb, bias, out);
    } else {
        cin_main<false><<<dim3(B_SZ), dim3(512), 0, stream>>>(x0, xl, W, Wb, bias, out);
    }
}

// Round 5
// 79.156 us; speedup vs baseline: 1.1665x; 1.1665x over previous
//
#include <hip/hip_runtime.h>
#include <hip/hip_bf16.h>
#include <stdint.h>

// out[b,o,k] = sum_{h,m} W[o, h*64+m] * xl[b,h,k] * x0[b,m,k] + bias[o]
// B=256, M=H=64, K=128, OUT=256, C=4096.
// v5: out = sum_h xl[h,n] * (W_h @ x0), 32x32x16 MFMA, BARRIER-FREE main loop.
//  - grid (2,256), 256 thr (4 waves); wave owns o-tile got=ohalf*4+wave, all k.
//  - W staging is per-wave-PRIVATE: global_load_lds into this wave's own LDS
//    ring (3 x 4KB); ordering via counted s_waitcnt vmcnt(4) only. No s_barrier
//    in the loop -> waves fully desynchronized, 2 blocks/CU overlap.
//  - x0 B-frags h-invariant in registers (64 VGPR); xl bf16 in LDS (16 KB,
//    one prologue barrier).

typedef __attribute__((ext_vector_type(8)))  short short8;
typedef __attribute__((ext_vector_type(16))) float f32x16;

#define B_SZ   256
#define K_SZ   128
#define OUT_SZ 256
#define C_SZ   4096
#define NH     64

__device__ __forceinline__ uint32_t pack_bf16(float a, float b) {
    __hip_bfloat162 h2 = __float22bfloat162_rn(make_float2(a, b));
    union { __hip_bfloat162 h; uint32_t u; } v;
    v.h = h2;
    return v.u;
}

__device__ __forceinline__ float bf2f(short s) {
    union { uint32_t u; float f; } v;
    v.u = ((uint32_t)(uint16_t)s) << 16;
    return v.f;
}

__device__ __forceinline__ void load_lds_16(const void* g, void* l) {
    __builtin_amdgcn_global_load_lds(
        (const __attribute__((address_space(1))) unsigned int*)g,
        (__attribute__((address_space(3))) unsigned int*)l,
        16, 0, 0);
}

// ---- W f32 -> bf16 tiled for 32x32x16 A-frags (same layout as v4) ----
// subtile = got*256 + cb16 (512 shorts, lane-linear):
//   element (o = got*32 + (lane&31), c = cb16*16 + (lane>>5)*8 + j)
__global__ void convert_W_tiled(const float* __restrict__ W, short* __restrict__ Wb) {
    int t = blockIdx.x * blockDim.x + threadIdx.x;   // 0..131071
    int lane = t & 63;
    int sub  = t >> 6;          // 0..2047
    int cb16 = sub & 255;
    int got  = sub >> 8;        // 0..7
    int o = got * 32 + (lane & 31);
    int c = cb16 * 16 + (lane >> 5) * 8;
    const float* p = W + (size_t)o * C_SZ + c;
    float4 w0 = *(const float4*)p;
    float4 w1 = *(const float4*)(p + 4);
    union { short8 s; uint32_t u[4]; } cc;
    cc.u[0] = pack_bf16(w0.x, w0.y);
    cc.u[1] = pack_bf16(w0.z, w0.w);
    cc.u[2] = pack_bf16(w1.x, w1.y);
    cc.u[3] = pack_bf16(w1.z, w1.w);
    *(short8*)(Wb + (size_t)t * 8) = cc.s;
}

template<bool USE_WS>
__global__ __launch_bounds__(256, 2)
void cin_main(const float* __restrict__ x0, const float* __restrict__ xl,
              const float* __restrict__ Wf, const short* __restrict__ Wb,
              const float* __restrict__ bias, float* __restrict__ out) {
    __shared__ short Wlds[4 * 3 * 2048];   // [wave][ringbuf 0..2][2048] = 48 KB
    __shared__ short xls[NH * K_SZ];       // 16 KB bf16 [h][k]

    const int b     = blockIdx.y;
    const int ohalf = blockIdx.x;
    const int tid   = threadIdx.x;
    const int lane  = tid & 63;
    const int wave  = tid >> 6;            // 0..3
    const int got   = ohalf * 4 + wave;    // o-tile 0..7
    const int l31   = lane & 31;
    const int hi    = lane >> 5;

    // ---- stage xl as bf16 into LDS (256 thr x 32 elems) ----
    {
        const float4* src = (const float4*)(xl + (size_t)b * (NH * K_SZ));
        uint32_t* dst = (uint32_t*)&xls[tid * 32];
#pragma unroll
        for (int i = 0; i < 8; ++i) {
            float4 v = src[tid * 8 + i];
            dst[2 * i]     = pack_bf16(v.x, v.y);
            dst[2 * i + 1] = pack_bf16(v.z, v.w);
        }
    }

    // ---- x0 B-frags (h-invariant), 32x32x16 layout: 64 VGPRs ----
    // x0p[s][nt].j = x0[m = s*16 + hi*8 + j][n = nt*32 + l31]
    union { short8 s; uint32_t u[4]; } x0p[4][4];
    {
        const float* x0b = x0 + (size_t)b * (64 * K_SZ);
#pragma unroll
        for (int s = 0; s < 4; ++s)
#pragma unroll
            for (int nt = 0; nt < 4; ++nt)
#pragma unroll
                for (int t2 = 0; t2 < 4; ++t2) {
                    const int m0 = s * 16 + hi * 8 + 2 * t2;
                    const int cc = nt * 32 + l31;
                    x0p[s][nt].u[t2] = pack_bf16(x0b[m0 * K_SZ + cc],
                                                 x0b[(m0 + 1) * K_SZ + cc]);
                }
    }

    // ---- per-wave-private W staging ----
    const short* wsrc  = Wb + ((size_t)got * 256) * 512 + lane * 8;
    const float* wfrow = Wf + (size_t)(got * 32 + l31) * C_SZ + hi * 8;
    short* wl = Wlds + wave * (3 * 2048);

    auto stage = [&](int buf, int h) {
        if (USE_WS) {
            const short* s0 = wsrc + (size_t)(4 * h) * 512;
            short* d = wl + buf * 2048;
#pragma unroll
            for (int sub = 0; sub < 4; ++sub)
                load_lds_16(s0 + sub * 512, d + sub * 512);
        } else {
#pragma unroll
            for (int sub = 0; sub < 4; ++sub) {
                const float* p = wfrow + h * 64 + sub * 16;
                float4 w0 = *(const float4*)p;
                float4 w1 = *(const float4*)(p + 4);
                union { short8 s; uint32_t u[4]; } cc;
                cc.u[0] = pack_bf16(w0.x, w0.y);
                cc.u[1] = pack_bf16(w0.z, w0.w);
                cc.u[2] = pack_bf16(w1.x, w1.y);
                cc.u[3] = pack_bf16(w1.z, w1.w);
                *(short8*)(wl + buf * 2048 + sub * 512 + lane * 8) = cc.s;
            }
        }
    };

    f32x16 acc[4];
#pragma unroll
    for (int nt = 0; nt < 4; ++nt)
#pragma unroll
        for (int r = 0; r < 16; ++r) acc[nt][r] = 0.f;
    f32x16 kz;
#pragma unroll
    for (int r = 0; r < 16; ++r) kz[r] = 0.f;

    // prologue: stage h=0,1 (8 loads in flight), one barrier for xls only
    stage(0, 0);
    stage(1, 1);
    __syncthreads();   // xls visible to all waves (also drains prologue loads)

    int buf = 0;
    for (int h = 0; h < NH; ++h) {
        // wait for this h's 4 loads (older than the 4 in-flight for h+1)
        if (USE_WS) asm volatile("s_waitcnt vmcnt(4)" ::: "memory");

        // wrap-stage keeps the vmcnt count uniform across all iterations
        int bn = buf + 2; if (bn >= 3) bn -= 3;
        stage(bn, (h + 2) & (NH - 1));

        const short* wb2 = wl + buf * 2048 + lane * 8;
        const short8 af0 = *(const short8*)(wb2);
        const short8 af1 = *(const short8*)(wb2 + 512);
        const short8 af2 = *(const short8*)(wb2 + 1024);
        const short8 af3 = *(const short8*)(wb2 + 1536);

        float xlv[4];
#pragma unroll
        for (int nt = 0; nt < 4; ++nt)
            xlv[nt] = bf2f(xls[h * K_SZ + nt * 32 + l31]);

#pragma unroll
        for (int nt = 0; nt < 4; ++nt) {
            f32x16 g = __builtin_amdgcn_mfma_f32_32x32x16_bf16(af0, x0p[0][nt].s, kz, 0, 0, 0);
            g = __builtin_amdgcn_mfma_f32_32x32x16_bf16(af1, x0p[1][nt].s, g, 0, 0, 0);
            g = __builtin_amdgcn_mfma_f32_32x32x16_bf16(af2, x0p[2][nt].s, g, 0, 0, 0);
            g = __builtin_amdgcn_mfma_f32_32x32x16_bf16(af3, x0p[3][nt].s, g, 0, 0, 0);
#pragma unroll
            for (int r = 0; r < 16; ++r)
                acc[nt][r] += xlv[nt] * g[r];
        }

        buf += 1; if (buf == 3) buf = 0;
    }

    // ---- epilogue: bias + store ----
    // 32x32 C/D: col(k) = l31, row(o) = (r&3) + 8*(r>>2) + 4*hi   [m74/m101]
    float bv[16];
#pragma unroll
    for (int r = 0; r < 16; ++r)
        bv[r] = bias[got * 32 + (r & 3) + 8 * (r >> 2) + 4 * hi];

    float* outb = out + (size_t)b * (OUT_SZ * K_SZ);
#pragma unroll
    for (int nt = 0; nt < 4; ++nt) {
        const int kcol = nt * 32 + l31;
#pragma unroll
        for (int r = 0; r < 16; ++r) {
            const int orow = got * 32 + (r & 3) + 8 * (r >> 2) + 4 * hi;
            outb[orow * K_SZ + kcol] = acc[nt][r] + bv[r];
        }
    }
}

extern "C" void kernel_launch(void* const* d_in, const int* in_sizes, int n_in,
                              void* d_out, int out_size, void* d_ws, size_t ws_size,
                              hipStream_t stream) {
    const float* x0   = (const float*)d_in[0];
    const float* xl   = (const float*)d_in[1];
    // d_in[2] is the scalar k (=128) — fixed by the problem shape
    const float* W    = (const float*)d_in[3];
    const float* bias = (const float*)d_in[4];
    float* out = (float*)d_out;

    const size_t w_bytes = (size_t)OUT_SZ * C_SZ * sizeof(short);
    short* Wb = (short*)d_ws;

    if (ws_size >= w_bytes) {
        convert_W_tiled<<<dim3(512), dim3(256), 0, stream>>>(W, Wb);
        cin_main<true><<<dim3(2, B_SZ), dim3(256), 0, stream>>>(x0, xl, W, Wb, bias, out);
    } else {
        cin_main<false><<<dim3(2, B_SZ), dim3(256), 0, stream>>>(x0, xl, W, Wb, bias, out);
    }
}